// Round 1
// baseline (357.552 us; speedup 1.0000x reference)
//
#include <hip/hip_runtime.h>

// Problem constants (fixed by setup_inputs): B=32, C=256, H=W=56
#define C_CH 256
#define B_N  32
#define HW   3136   // 56*56
#define HW4  784    // HW/4 (float4 granules per plane)

// ---------------------------------------------------------------------------
// Kernel 1: compute per-channel source-selection tables (runs once per call).
// sel[0..255]   : for feature1 -> source channel in x2, or -1 (keep x1[c])
// sel[256..511] : for feature2 -> source channel in x1, or -1 (keep x2[c])
// Semantics match jnp stable argsort(-|w|): rank = #{j: a[j]>a[i]} +
// #{j<i: a[j]==a[i]}  (descending, ties broken by lower original index).
// ---------------------------------------------------------------------------
__global__ void setup_sel_kernel(const float* __restrict__ w1,
                                 const float* __restrict__ w2,
                                 const float* __restrict__ thr_p,
                                 int* __restrict__ sel)
{
    __shared__ float a1[C_CH], a2[C_CH];
    __shared__ int order1[C_CH], order2[C_CH];
    __shared__ int cum1[C_CH], cum2[C_CH];

    const int i = threadIdx.x;
    a1[i] = fabsf(w1[i]);
    a2[i] = fabsf(w2[i]);
    __syncthreads();

    const float v1 = a1[i], v2 = a2[i];
    int r1 = 0, r2 = 0;
    #pragma unroll 8
    for (int j = 0; j < C_CH; ++j) {
        const float b1 = a1[j], b2 = a2[j];
        r1 += (b1 > v1) || (b1 == v1 && j < i);
        r2 += (b2 > v2) || (b2 == v2 && j < i);
    }
    order1[r1] = i;   // order1[k] = channel with k-th largest |w1|
    order2[r2] = i;

    const float thr = thr_p[0];
    const int below1 = (v1 < thr) ? 1 : 0;
    const int below2 = (v2 < thr) ? 1 : 0;
    cum1[i] = below1;
    cum2[i] = below2;
    __syncthreads();

    // 256-element serial inclusive scan in thread 0 — negligible cost.
    if (i == 0) {
        int s1 = 0, s2 = 0;
        for (int j = 0; j < C_CH; ++j) {
            s1 += cum1[j]; cum1[j] = s1;
            s2 += cum2[j]; cum2[j] = s2;
        }
    }
    __syncthreads();

    int rk1 = cum1[i] - 1; if (rk1 < 0) rk1 = 0;   // clip(cumsum-1, 0)
    int rk2 = cum2[i] - 1; if (rk2 < 0) rk2 = 0;

    sel[i]        = below1 ? order2[rk1] : -1;
    sel[C_CH + i] = below1 ? sel[i] : sel[i]; // placeholder removed below
    sel[C_CH + i] = below2 ? order1[rk2] : -1;
}

// ---------------------------------------------------------------------------
// Kernel 2: plane copy/gather. One block per (output, b, c) plane.
// grid = 2*B*C = 16384 blocks (power-of-two decode), 256 threads/block.
// Whole plane reads from ONE source channel -> block-uniform branch,
// fully coalesced float4 traffic.
// ---------------------------------------------------------------------------
__global__ __launch_bounds__(256)
void gather_planes_kernel(const float4* __restrict__ x1,
                          const float4* __restrict__ x2,
                          const int*    __restrict__ sel,
                          float4*       __restrict__ out)
{
    const unsigned blk = blockIdx.x;
    const int out_id = blk >> 13;        // 0 -> feature1, 1 -> feature2 (8192 = B*C)
    const int bc     = blk & 8191;       // b*C + c
    const int c      = bc & 255;
    const size_t b   = (size_t)(bc >> 8);

    const float4* primary = out_id ? x2 : x1;
    const float4* other   = out_id ? x1 : x2;

    const int s = sel[out_id * C_CH + c];

    const float4* src = (s >= 0)
        ? other + (b * C_CH + (size_t)s) * HW4
        : primary + (size_t)bc * HW4;

    float4* dst = out + ((size_t)out_id * (B_N * C_CH) + (size_t)bc) * HW4;

    for (int t = threadIdx.x; t < HW4; t += 256) {
        dst[t] = src[t];
    }
}

extern "C" void kernel_launch(void* const* d_in, const int* in_sizes, int n_in,
                              void* d_out, int out_size, void* d_ws, size_t ws_size,
                              hipStream_t stream)
{
    const float* x1  = (const float*)d_in[0];
    const float* x2  = (const float*)d_in[1];
    const float* w1  = (const float*)d_in[2];
    const float* w2  = (const float*)d_in[3];
    const float* thr = (const float*)d_in[4];

    int* sel = (int*)d_ws;   // 512 ints = 2 KiB of scratch

    setup_sel_kernel<<<1, C_CH, 0, stream>>>(w1, w2, thr, sel);

    gather_planes_kernel<<<2 * B_N * C_CH, 256, 0, stream>>>(
        (const float4*)x1, (const float4*)x2, sel, (float4*)d_out);
}

// Round 2
// 342.618 us; speedup vs baseline: 1.0436x; 1.0436x over previous
//
#include <hip/hip_runtime.h>

// Problem constants (fixed by setup_inputs): B=32, C=256, H=W=56
#define C_CH 256
#define B_N  32
#define HW   3136   // 56*56
#define HW4  784    // HW/4 (float4 granules per plane) = 3*256 + 16

typedef float v4f __attribute__((ext_vector_type(4)));

// ---------------------------------------------------------------------------
// Kernel 1: per-channel source-selection tables.
// sel[0..255]   : feature1 -> source channel in x2, or -1 (keep x1[c])
// sel[256..511] : feature2 -> source channel in x1, or -1 (keep x2[c])
// rank = #{j: a[j]>a[i]} + #{j<i: a[j]==a[i]}  (stable descending argsort).
// Parallel Hillis-Steele scan replaces the previous serial thread-0 scan
// (which was ~50 us of single-wave LDS latency).
// ---------------------------------------------------------------------------
__global__ void setup_sel_kernel(const float* __restrict__ w1,
                                 const float* __restrict__ w2,
                                 const float* __restrict__ thr_p,
                                 int* __restrict__ sel)
{
    __shared__ float a1[C_CH], a2[C_CH];
    __shared__ int order1[C_CH], order2[C_CH];
    __shared__ int cum1[C_CH], cum2[C_CH];

    const int i = threadIdx.x;
    a1[i] = fabsf(w1[i]);
    a2[i] = fabsf(w2[i]);
    __syncthreads();

    const float v1 = a1[i], v2 = a2[i];
    int r1 = 0, r2 = 0;
    #pragma unroll 16
    for (int j = 0; j < C_CH; ++j) {
        const float b1 = a1[j], b2 = a2[j];
        r1 += (b1 > v1) || (b1 == v1 && j < i);
        r2 += (b2 > v2) || (b2 == v2 && j < i);
    }
    order1[r1] = i;   // order1[k] = channel with k-th largest |w1|
    order2[r2] = i;

    const float thr = thr_p[0];
    const int below1 = (v1 < thr) ? 1 : 0;
    const int below2 = (v2 < thr) ? 1 : 0;
    cum1[i] = below1;
    cum2[i] = below2;
    __syncthreads();

    // Inclusive parallel scan over 256 elements (8 steps).
    #pragma unroll
    for (int off = 1; off < C_CH; off <<= 1) {
        const int t1 = (i >= off) ? cum1[i - off] : 0;
        const int t2 = (i >= off) ? cum2[i - off] : 0;
        __syncthreads();
        cum1[i] += t1;
        cum2[i] += t2;
        __syncthreads();
    }

    int rk1 = cum1[i] - 1; if (rk1 < 0) rk1 = 0;   // clip(cumsum-1, 0)
    int rk2 = cum2[i] - 1; if (rk2 < 0) rk2 = 0;

    sel[i]        = below1 ? order2[rk1] : -1;
    sel[C_CH + i] = below2 ? order1[rk2] : -1;
}

// ---------------------------------------------------------------------------
// Kernel 2: plane copy/gather. One block per (output, b, c) plane.
// grid = 2*B*C = 16384 blocks, 256 threads. Block-uniform source selection,
// fully coalesced float4 traffic, nontemporal (streaming, zero-reuse) hints.
// 784 granules = 3 full rounds + 16-lane tail; loads issued before stores.
// ---------------------------------------------------------------------------
__global__ __launch_bounds__(256)
void gather_planes_kernel(const v4f* __restrict__ x1,
                          const v4f* __restrict__ x2,
                          const int* __restrict__ sel,
                          v4f*       __restrict__ out)
{
    const unsigned blk = blockIdx.x;
    const int out_id = blk >> 13;        // 0 -> feature1, 1 -> feature2 (8192 = B*C)
    const int bc     = blk & 8191;       // b*C + c
    const int c      = bc & 255;
    const size_t b   = (size_t)(bc >> 8);

    const v4f* primary = out_id ? x2 : x1;
    const v4f* other   = out_id ? x1 : x2;

    const int s = sel[out_id * C_CH + c];

    const v4f* src = (s >= 0)
        ? other + (b * C_CH + (size_t)s) * HW4
        : primary + (size_t)bc * HW4;

    v4f* dst = out + ((size_t)out_id * (B_N * C_CH) + (size_t)bc) * HW4;

    const int t = threadIdx.x;
    const v4f r0 = __builtin_nontemporal_load(src + t);
    const v4f r1 = __builtin_nontemporal_load(src + t + 256);
    const v4f r2 = __builtin_nontemporal_load(src + t + 512);
    __builtin_nontemporal_store(r0, dst + t);
    __builtin_nontemporal_store(r1, dst + t + 256);
    __builtin_nontemporal_store(r2, dst + t + 512);
    if (t < 16) {
        const v4f r3 = __builtin_nontemporal_load(src + t + 768);
        __builtin_nontemporal_store(r3, dst + t + 768);
    }
}

extern "C" void kernel_launch(void* const* d_in, const int* in_sizes, int n_in,
                              void* d_out, int out_size, void* d_ws, size_t ws_size,
                              hipStream_t stream)
{
    const float* x1  = (const float*)d_in[0];
    const float* x2  = (const float*)d_in[1];
    const float* w1  = (const float*)d_in[2];
    const float* w2  = (const float*)d_in[3];
    const float* thr = (const float*)d_in[4];

    int* sel = (int*)d_ws;   // 512 ints = 2 KiB of scratch

    setup_sel_kernel<<<1, C_CH, 0, stream>>>(w1, w2, thr, sel);

    gather_planes_kernel<<<2 * B_N * C_CH, 256, 0, stream>>>(
        (const v4f*)x1, (const v4f*)x2, sel, (v4f*)d_out);
}